// Round 1
// baseline (74.309 us; speedup 1.0000x reference)
//
#include <hip/hip_runtime.h>

// Problem constants (from reference setup_inputs):
//   user_attributes: [B=32, U=128, D=256] fp32
//   image_attributes:[B=32, I=256, D=256] fp32
// out = concat(out_user [B,U,D], out_img [B,I,D]) flat fp32
#define B 32
#define U 128
#define I 256
#define D 256

// d_ws layout: [0 .. B*D)        user_sum[b,d]  (sum over u)
//              [B*D .. 2*B*D)    img_sum[b,d]   (sum over i)

// Reduce kernel: blocks 0..127 handle user (b = blk/4, 32-row chunk = blk%4)
//                blocks 128..383 handle img (b = (blk-128)/8, 32-row chunk)
// 256 threads = 4 waves; each wave loads full 1KB rows as float4 (coalesced),
// LDS-combines the 4 row-group partials, then one atomicAdd per column.
__global__ void __launch_bounds__(256) reduce_sums_kernel(
    const float* __restrict__ user,
    const float* __restrict__ img,
    float* __restrict__ sums) {
  __shared__ float4 part[4][64];
  const int blk  = blockIdx.x;
  const int tid  = threadIdx.x;
  const int rg   = tid >> 6;   // row-group / wave id 0..3
  const int lane = tid & 63;   // float4 column index 0..63

  const float4* src4;
  float* dst;
  int r0;
  if (blk < 128) {                      // user: 4 chunks of 32 rows per b
    const int b = blk >> 2;
    r0 = (blk & 3) * 32;
    src4 = (const float4*)(user + (size_t)b * U * D);
    dst  = sums + b * D;                // user_sum
  } else {                              // img: 8 chunks of 32 rows per b
    const int k = blk - 128;
    const int b = k >> 3;
    r0 = (k & 7) * 32;
    src4 = (const float4*)(img + (size_t)b * I * D);
    dst  = sums + B * D + b * D;        // img_sum
  }

  float4 acc = make_float4(0.f, 0.f, 0.f, 0.f);
  // each wave covers rows r0+rg*8 .. r0+rg*8+7; one row = 64 float4
  for (int it = 0; it < 8; ++it) {
    const int r = r0 + rg * 8 + it;
    const float4 v = src4[(size_t)r * 64 + lane];
    acc.x += v.x; acc.y += v.y; acc.z += v.z; acc.w += v.w;
  }
  part[rg][lane] = acc;
  __syncthreads();
  if (rg == 0) {
    const float4 a = part[0][lane];
    const float4 b4 = part[1][lane];
    const float4 c = part[2][lane];
    const float4 e = part[3][lane];
    atomicAdd(dst + lane * 4 + 0, a.x + b4.x + c.x + e.x);
    atomicAdd(dst + lane * 4 + 1, a.y + b4.y + c.y + e.y);
    atomicAdd(dst + lane * 4 + 2, a.z + b4.z + c.z + e.z);
    atomicAdd(dst + lane * 4 + 3, a.w + b4.w + c.w + e.w);
  }
}

// Elementwise multiply: flat float4 grid over both outputs.
__global__ void __launch_bounds__(256) multiply_kernel(
    const float* __restrict__ user,
    const float* __restrict__ img,
    const float* __restrict__ sums,
    float* __restrict__ out) {
  constexpr int U4  = U * D / 4;   // 8192 float4 per batch (user)
  constexpr int I4  = I * D / 4;   // 16384 float4 per batch (img)
  constexpr int NU4 = B * U4;      // 262144
  constexpr int NI4 = B * I4;      // 524288

  const int g = blockIdx.x * blockDim.x + threadIdx.x;
  const float4* u4  = (const float4*)user;
  const float4* i4  = (const float4*)img;
  const float4* us4 = (const float4*)sums;            // user_sum as [B*64] float4
  const float4* is4 = (const float4*)(sums + B * D);  // img_sum  as [B*64] float4
  float4* o4 = (float4*)out;

  if (g < NU4) {
    const int b  = g >> 13;        // / 8192
    const int d4 = g & 63;
    const float4 v = u4[g];
    const float4 s = is4[b * 64 + d4];   // img_sum
    o4[g] = make_float4(v.x * s.x, v.y * s.y, v.z * s.z, v.w * s.w);
  } else if (g < NU4 + NI4) {
    const int k  = g - NU4;
    const int b  = k >> 14;        // / 16384
    const int d4 = k & 63;
    const float4 v = i4[k];
    const float4 s = us4[b * 64 + d4];   // user_sum
    o4[NU4 + k] = make_float4(v.x * s.x, v.y * s.y, v.z * s.z, v.w * s.w);
  }
}

extern "C" void kernel_launch(void* const* d_in, const int* in_sizes, int n_in,
                              void* d_out, int out_size, void* d_ws, size_t ws_size,
                              hipStream_t stream) {
  const float* user = (const float*)d_in[0];
  const float* img  = (const float*)d_in[1];
  float* out  = (float*)d_out;
  float* sums = (float*)d_ws;

  // zero the 2*B*D sum buffer (ws is re-poisoned to 0xAA before every launch)
  hipMemsetAsync(d_ws, 0, 2 * B * D * sizeof(float), stream);

  reduce_sums_kernel<<<dim3(384), dim3(256), 0, stream>>>(user, img, sums);

  constexpr int total4 = (B * U * D + B * I * D) / 4;  // 786432
  multiply_kernel<<<dim3(total4 / 256), dim3(256), 0, stream>>>(user, img, sums, out);
}

// Round 2
// 71.163 us; speedup vs baseline: 1.0442x; 1.0442x over previous
//
#include <hip/hip_runtime.h>

// Problem: inter[b,u,i,d] = user[b,u,d]*img[b,i,d], summed over i (-> out_user)
// and over u (-> out_img).
//   user: [B=32, U=128, D=256] fp32,  img: [B=32, I=256, D=256] fp32
//   out = concat(out_user [B,U,D], out_img [B,I,D]) flat fp32
#define B 32
#define U 128
#define I 256
#define D 256

// d_ws layout (floats):
//   [0 .. B*4*D)          user partial sums  [b][chunk 0..3][d]
//   [B*4*D .. B*4*D+B*8*D) img partial sums  [b][chunk 0..7][d]
// No zero-init needed: partials are written with plain stores.
#define PU_OFF 0
#define PI_OFF (B * 4 * D)

// Reduce kernel: blocks 0..127 -> user (b = blk/4, 32-row chunk = blk%4)
//                blocks 128..383 -> img (b = (blk-128)/8, 32-row chunk)
// 256 threads = 4 waves; each wave sums 8 full rows as float4 (coalesced),
// LDS-combines the 4 wave partials, wave 0 stores one 1KB partial vector.
__global__ void __launch_bounds__(256) reduce_partial_kernel(
    const float* __restrict__ user,
    const float* __restrict__ img,
    float* __restrict__ ws) {
  __shared__ float4 part[4][64];
  const int blk  = blockIdx.x;
  const int tid  = threadIdx.x;
  const int rg   = tid >> 6;   // wave id 0..3
  const int lane = tid & 63;   // float4 column index 0..63

  const float4* src4;
  float4* dst4;
  if (blk < 128) {                         // user: 4 chunks of 32 rows per b
    const int b = blk >> 2, c = blk & 3;
    src4 = (const float4*)(user + (size_t)b * U * D) + (size_t)c * 32 * 64;
    dst4 = (float4*)(ws + PU_OFF) + (size_t)(b * 4 + c) * 64;
  } else {                                 // img: 8 chunks of 32 rows per b
    const int k = blk - 128;
    const int b = k >> 3, c = k & 7;
    src4 = (const float4*)(img + (size_t)b * I * D) + (size_t)c * 32 * 64;
    dst4 = (float4*)(ws + PI_OFF) + (size_t)(b * 8 + c) * 64;
  }

  float4 acc = make_float4(0.f, 0.f, 0.f, 0.f);
  // wave rg covers rows rg*8 .. rg*8+7 of this 32-row chunk; one row = 64 float4
  #pragma unroll
  for (int it = 0; it < 8; ++it) {
    const float4 v = src4[(size_t)(rg * 8 + it) * 64 + lane];
    acc.x += v.x; acc.y += v.y; acc.z += v.z; acc.w += v.w;
  }
  part[rg][lane] = acc;
  __syncthreads();
  if (rg == 0) {
    const float4 a = part[0][lane];
    const float4 b4 = part[1][lane];
    const float4 c = part[2][lane];
    const float4 e = part[3][lane];
    dst4[lane] = make_float4(a.x + b4.x + c.x + e.x,
                             a.y + b4.y + c.y + e.y,
                             a.z + b4.z + c.z + e.z,
                             a.w + b4.w + c.w + e.w);
  }
}

// Multiply kernel: flat float4 grid over both outputs; folds the partial-sum
// combine (4 or 8 L2-hot float4 loads) into the elementwise scale.
__global__ void __launch_bounds__(256) multiply_kernel(
    const float* __restrict__ user,
    const float* __restrict__ img,
    const float* __restrict__ ws,
    float* __restrict__ out) {
  constexpr int U4  = U * D / 4;   // 8192 float4 per batch (user)
  constexpr int I4  = I * D / 4;   // 16384 float4 per batch (img)
  constexpr int NU4 = B * U4;      // 262144
  constexpr int NI4 = B * I4;      // 524288

  const int g = blockIdx.x * blockDim.x + threadIdx.x;
  const float4* u4  = (const float4*)user;
  const float4* i4  = (const float4*)img;
  const float4* pu4 = (const float4*)(ws + PU_OFF);  // [B*4][64] float4
  const float4* pi4 = (const float4*)(ws + PI_OFF);  // [B*8][64] float4
  float4* o4 = (float4*)out;

  if (g < NU4) {
    // out_user[b,u,d] = user[b,u,d] * img_sum[b,d]  (sum 8 img partials)
    const int b  = g >> 13;        // / 8192
    const int d4 = g & 63;
    const float4* p = pi4 + (size_t)b * 8 * 64 + d4;
    float4 s = p[0];
    #pragma unroll
    for (int c = 1; c < 8; ++c) {
      const float4 t = p[(size_t)c * 64];
      s.x += t.x; s.y += t.y; s.z += t.z; s.w += t.w;
    }
    const float4 v = u4[g];
    o4[g] = make_float4(v.x * s.x, v.y * s.y, v.z * s.z, v.w * s.w);
  } else if (g < NU4 + NI4) {
    // out_img[b,i,d] = img[b,i,d] * user_sum[b,d]  (sum 4 user partials)
    const int k  = g - NU4;
    const int b  = k >> 14;        // / 16384
    const int d4 = k & 63;
    const float4* p = pu4 + (size_t)b * 4 * 64 + d4;
    float4 s = p[0];
    #pragma unroll
    for (int c = 1; c < 4; ++c) {
      const float4 t = p[(size_t)c * 64];
      s.x += t.x; s.y += t.y; s.z += t.z; s.w += t.w;
    }
    const float4 v = i4[k];
    o4[NU4 + k] = make_float4(v.x * s.x, v.y * s.y, v.z * s.z, v.w * s.w);
  }
}

extern "C" void kernel_launch(void* const* d_in, const int* in_sizes, int n_in,
                              void* d_out, int out_size, void* d_ws, size_t ws_size,
                              hipStream_t stream) {
  const float* user = (const float*)d_in[0];
  const float* img  = (const float*)d_in[1];
  float* out = (float*)d_out;
  float* ws  = (float*)d_ws;

  reduce_partial_kernel<<<dim3(384), dim3(256), 0, stream>>>(user, img, ws);

  constexpr int total4 = (B * U * D + B * I * D) / 4;  // 786432
  multiply_kernel<<<dim3(total4 / 256), dim3(256), 0, stream>>>(user, img, ws, out);
}